// Round 4
// baseline (207.762 us; speedup 1.0000x reference)
//
#include <hip/hip_runtime.h>

#define BSZ  8192
#define DDIM 256
#define NCLS 1024
#define BM 128
#define BN 128
#define NT   64                  // tiles per dimension
#define NTRI (NT * (NT + 1) / 2) // 2080 upper-triangle tiles
#define MAXH 128                 // class-size cap (Poisson(8), P(h>128) ~ 0)

typedef float f32x4 __attribute__((ext_vector_type(4)));
typedef short bf16x8 __attribute__((ext_vector_type(8)));

__device__ __forceinline__ unsigned short f32_to_bf16(float f) {
    unsigned int u = __float_as_uint(f);
    u += 0x7fffu + ((u >> 16) & 1u);   // RNE
    return (unsigned short)(u >> 16);
}
__device__ __forceinline__ float bf2f(unsigned short u) {
    return __uint_as_float(((unsigned int)u) << 16);
}

// epilogue constants
#define K_E1  20.60992915555662f    // (1/T)*log2(e)
#define K_E2 -20.60992915555662f
#define K_N1  1.4285714285714286f   // 1/(1-0.3)
#define K_N2  0.5714285714285714f   // 0.4/0.7

// ---------------- L2-normalize rows; emit row-major bf16 + MFMA-native layout ----------------
// anchorT layout: tile (C = k/32, R = row/16) stored at ((C*512 + R) * 512) shorts,
// within-tile lane l = (row%16) + 16*((k%32)/8) holds elems j=0..7 (k = C*32 + (l/16)*8 + j).
// A- and B-operand layouts of mfma_f32_16x16x32_bf16 are both exactly this.
__global__ __launch_bounds__(256) void norm_kernel(const float* __restrict__ feat,
                                                   unsigned short* __restrict__ anchor,
                                                   unsigned short* __restrict__ anchorT) {
    const int wid  = threadIdx.x >> 6;
    const int lane = threadIdx.x & 63;
    const int row  = blockIdx.x * 4 + wid;
    const float4 v = ((const float4*)(feat + (size_t)row * DDIM))[lane];
    float ss = v.x * v.x + v.y * v.y + v.z * v.z + v.w * v.w;
    #pragma unroll
    for (int off = 32; off > 0; off >>= 1) ss += __shfl_xor(ss, off, 64);
    const float inv = rsqrtf(ss);
    ushort4 o;
    o.x = f32_to_bf16(v.x * inv);
    o.y = f32_to_bf16(v.y * inv);
    o.z = f32_to_bf16(v.z * inv);
    o.w = f32_to_bf16(v.w * inv);
    ((ushort4*)(anchor + (size_t)row * DDIM))[lane] = o;
    // fragment-native copy: this thread's 4 elems are k = lane*4 .. +3
    const int C    = lane >> 3;                       // k / 32
    const int tile = C * 512 + (row >> 4);
    const int l16  = (row & 15) + (((lane >> 1) & 3) << 4);
    *(ushort4*)(anchorT + (size_t)tile * 512 + l16 * 8 + (lane & 1) * 4) = o;
}

template <bool DIAG>
__device__ __forceinline__ void epilogue(
    const f32x4 (&c_acc)[4][4], int rg, int cl, int waveM, int waveN, bool dwave,
    float (*rowPart)[BM][2], float (*colPart)[BN][2])
{
    float cd[4] = {0.f, 0.f, 0.f, 0.f}, ct[4] = {0.f, 0.f, 0.f, 0.f};
    #pragma unroll
    for (int fr = 0; fr < 4; fr++) {
        float rd[4] = {0.f, 0.f, 0.f, 0.f}, rt[4] = {0.f, 0.f, 0.f, 0.f};
        #pragma unroll
        for (int fc = 0; fc < 4; fc++) {
            const f32x4 c = c_acc[fr][fc];
            #pragma unroll
            for (int r = 0; r < 4; r++) {
                const float s = c[r];
                float e = exp2f(fmaf(s, K_E1, K_E2));
                if (DIAG) {
                    if (fr == fc && dwave && (rg * 4 + r) == cl) e = 0.0f;  // self
                }
                const float wn = fmaxf(fmaf(s, K_N1, K_N2), 1.0f);
                const float we = wn * e;
                rd[r] += e;  rt[r] += we;
                if (!DIAG) { cd[fc] += e; ct[fc] += we; }
            }
        }
        #pragma unroll
        for (int r = 0; r < 4; r++) {
            #pragma unroll
            for (int off = 1; off < 16; off <<= 1) {
                rd[r] += __shfl_xor(rd[r], off, 64);
                rt[r] += __shfl_xor(rt[r], off, 64);
            }
        }
        if (cl == 0) {
            const int wh = waveN >> 6;
            #pragma unroll
            for (int r = 0; r < 4; r++) {
                const int row = waveM + fr * 16 + rg * 4 + r;
                rowPart[wh][row][0] = rd[r];
                rowPart[wh][row][1] = rt[r];
            }
        }
    }
    if (!DIAG) {
        #pragma unroll
        for (int fc = 0; fc < 4; fc++) {
            #pragma unroll
            for (int off = 16; off < 64; off <<= 1) {
                cd[fc] += __shfl_xor(cd[fc], off, 64);
                ct[fc] += __shfl_xor(ct[fc], off, 64);
            }
        }
        if (rg == 0) {
            const int wmh = waveM >> 6;
            #pragma unroll
            for (int fc = 0; fc < 4; fc++) {
                const int col = waveN + fc * 16 + cl;
                colPart[wmh][col][0] = cd[fc];
                colPart[wmh][col][1] = ct[fc];
            }
        }
    }
}

// ---------------- fused sim-tile + loss partials (upper triangle, no LDS matmul) ----------------
// part[Jt][row][{0:dsum, 1:T2}]; every (slab,row) written exactly once.
__global__ __launch_bounds__(256, 3) void simloss_kernel(
    const unsigned short* __restrict__ anchorT,
    float* __restrict__ part)
{
    __shared__ float rowPart[2][BM][2];
    __shared__ float colPart[2][BN][2];

    // triangular decode: block t -> (It <= Jt)
    const int t = blockIdx.x;
    int It = (int)((129.0 - sqrt(16641.0 - 8.0 * (double)t)) * 0.5);
    if (It > 63) It = 63; if (It < 0) It = 0;
    #define CFUN(i) (64 * (i) - ((i) * ((i) - 1)) / 2)
    while (It < 63 && CFUN(It + 1) <= t) ++It;
    while (It > 0 && CFUN(It) > t) --It;
    const int Jt = It + (t - CFUN(It));
    const bool diag = (It == Jt);

    const int tid  = threadIdx.x;
    const int wid  = tid >> 6;
    const int lane = tid & 63;
    const int waveM = (wid >> 1) * 64;   // 2x2 wave grid over 128x128
    const int waveN = (wid & 1) * 64;
    const int cl = lane & 15;            // column within 16x16 frag
    const int rg = lane >> 4;            // row group (rows rg*4 + r)
    const bool dwave = diag && (waveM == waveN);

    // per-lane fragment bases (1 KB coalesced load per fragment)
    const unsigned short* aBase = anchorT + (size_t)(It * 8 + (waveM >> 4)) * 512 + lane * 8;
    const unsigned short* bBase = anchorT + (size_t)(Jt * 8 + (waveN >> 4)) * 512 + lane * 8;

    f32x4 c_acc[4][4];
    #pragma unroll
    for (int a = 0; a < 4; a++)
        #pragma unroll
        for (int b = 0; b < 4; b++)
            c_acc[a][b] = (f32x4){0.f, 0.f, 0.f, 0.f};

    bf16x8 af[2][4], bfr[2][4];
    #pragma unroll
    for (int f = 0; f < 4; f++) {
        af[0][f]  = *(const bf16x8*)(aBase + f * 512);
        bfr[0][f] = *(const bf16x8*)(bBase + f * 512);
    }
    #pragma unroll
    for (int ks = 0; ks < 8; ks++) {
        const int cur = ks & 1, nxt = cur ^ 1;
        if (ks < 7) {
            const size_t adv = (size_t)(ks + 1) * (512 * 512);  // next K-chunk
            #pragma unroll
            for (int f = 0; f < 4; f++) {
                af[nxt][f]  = *(const bf16x8*)(aBase + adv + f * 512);
                bfr[nxt][f] = *(const bf16x8*)(bBase + adv + f * 512);
            }
        }
        #pragma unroll
        for (int fr = 0; fr < 4; fr++)
            #pragma unroll
            for (int fc = 0; fc < 4; fc++)
                c_acc[fr][fc] = __builtin_amdgcn_mfma_f32_16x16x32_bf16(
                    af[cur][fr], bfr[cur][fc], c_acc[fr][fc], 0, 0, 0);
    }

    if (diag) epilogue<true>(c_acc, rg, cl, waveM, waveN, dwave, rowPart, colPart);
    else      epilogue<false>(c_acc, rg, cl, waveM, waveN, dwave, rowPart, colPart);

    __syncthreads();
    const int I0 = It * BM, J0 = Jt * BN;
    if (tid < BM) {
        float2 v;
        v.x = rowPart[0][tid][0] + rowPart[1][tid][0];
        v.y = rowPart[0][tid][1] + rowPart[1][tid][1];
        ((float2*)part)[(size_t)Jt * BSZ + I0 + tid] = v;
    } else if (!diag) {
        const int c = tid - BM;
        float2 v;
        v.x = colPart[0][c][0] + colPart[1][c][0];
        v.y = colPart[0][c][1] + colPart[1][c][1];
        ((float2*)part)[(size_t)It * BSZ + J0 + c] = v;
    }
}

// ---------------- per-class positive terms (no atomics: one class owns each row) ----------------
// posout[row] = {s1, w1, pcorr, h}
__global__ __launch_bounds__(256) void posfix_kernel(
    const unsigned short* __restrict__ anchor,
    const int* __restrict__ labels,
    float* __restrict__ posout)
{
    __shared__ int rows[MAXH];
    __shared__ int cnt;
    const int c = blockIdx.x;
    const int tid = threadIdx.x;
    if (tid == 0) cnt = 0;
    __syncthreads();
    for (int i = tid; i < BSZ; i += 256)
        if (labels[i] == c) { int p = atomicAdd(&cnt, 1); if (p < MAXH) rows[p] = i; }
    __syncthreads();
    const int h = cnt < MAXH ? cnt : MAXH;
    if (h == 0) return;
    const int wid = tid >> 6, lane = tid & 63;
    for (int a = wid; a < h; a += 4) {
        const int ra = rows[a];
        const ushort4 va = ((const ushort4*)(anchor + (size_t)ra * DDIM))[lane];
        const float a0 = bf2f(va.x), a1 = bf2f(va.y), a2 = bf2f(va.z), a3 = bf2f(va.w);
        float s1 = 0.f, w1 = 0.f, pcorr = 0.f;
        for (int b = 0; b < h; b++) {
            if (b == a) continue;
            const int rb = rows[b];
            const ushort4 vb = ((const ushort4*)(anchor + (size_t)rb * DDIM))[lane];
            float d = a0 * bf2f(vb.x) + a1 * bf2f(vb.y) + a2 * bf2f(vb.z) + a3 * bf2f(vb.w);
            #pragma unroll
            for (int o = 32; o > 0; o >>= 1) d += __shfl_xor(d, o, 64);
            const float s  = d;
            const float e  = exp2f(fmaf(s, K_E1, K_E2));
            const float lp = (s - 1.0f) * 14.285714285714286f;
            const float wp = fmaxf(1.5f - s, 1.0f);
            const float wn = fmaxf(fmaf(s, K_N1, K_N2), 1.0f);
            s1 = fmaf(wp, lp, s1);
            w1 += wp;
            pcorr = fmaf(wn, e, pcorr);
        }
        if (lane == 0) {
            float4 o; o.x = s1; o.y = w1; o.z = pcorr; o.w = (float)h;
            ((float4*)posout)[ra] = o;
        }
    }
}

// ---------------- per-row combine + block partial sums ----------------
__global__ __launch_bounds__(256) void reduce_kernel(
    const float* __restrict__ part, const float* __restrict__ posout,
    double* __restrict__ partial)
{
    const int i = blockIdx.x * 256 + threadIdx.x;
    float dsum = 0.f, T2 = 0.f;
    const float2* p2 = (const float2*)part;
    #pragma unroll 8
    for (int j = 0; j < NT; j++) {
        const float2 v = p2[(size_t)j * BSZ + i];
        dsum += v.x; T2 += v.y;
    }
    const float4 po = ((const float4*)posout)[i];
    const float s1 = po.x, w1 = po.y, pcorr = po.z;
    const int h = (int)po.w;
    const float pc = fmaxf((float)(h - 1), 1.0f);
    const float nc = fmaxf((float)(BSZ - h), 1.0f);
    const float ld = logf(dsum);
    const double pos_i = (double)((s1 - ld * w1) / pc);
    const double neg_i = (double)(((T2 - pcorr) / dsum) / nc);

    __shared__ double sp[256], sn[256];
    sp[threadIdx.x] = pos_i; sn[threadIdx.x] = neg_i;
    __syncthreads();
    for (int s = 128; s > 0; s >>= 1) {
        if (threadIdx.x < s) {
            sp[threadIdx.x] += sp[threadIdx.x + s];
            sn[threadIdx.x] += sn[threadIdx.x + s];
        }
        __syncthreads();
    }
    if (threadIdx.x == 0) {
        partial[blockIdx.x * 2 + 0] = sp[0];
        partial[blockIdx.x * 2 + 1] = sn[0];
    }
}

// ---------------- final scalar ----------------
__global__ __launch_bounds__(64) void final_kernel(const double* __restrict__ partial,
                                                   float* __restrict__ out) {
    const int lane = threadIdx.x;
    double p = 0.0, n = 0.0;
    if (lane < 32) { p = partial[lane * 2 + 0]; n = partial[lane * 2 + 1]; }
    #pragma unroll
    for (int o = 32; o > 0; o >>= 1) { p += __shfl_xor(p, o, 64); n += __shfl_xor(n, o, 64); }
    if (lane == 0) out[0] = (float)(-p / (double)BSZ + 0.3 * (n / (double)BSZ));
}

extern "C" void kernel_launch(void* const* d_in, const int* in_sizes, int n_in,
                              void* d_out, int out_size, void* d_ws, size_t ws_size,
                              hipStream_t stream) {
    const float* feat = (const float*)d_in[0];
    const int* labels = (const int*)d_in[1];
    float* out = (float*)d_out;

    char* ws = (char*)d_ws;
    unsigned short* anchor = (unsigned short*)ws;                        // 4 MB bf16 row-major
    const size_t anchorBytes = (size_t)BSZ * DDIM * sizeof(unsigned short);
    unsigned short* anchorT = (unsigned short*)(ws + anchorBytes);       // 4 MB MFMA-native
    float* part = (float*)(ws + 2 * anchorBytes);                        // 64*8192*2 f32 = 4 MB
    const size_t partBytes = (size_t)NT * BSZ * 2 * sizeof(float);
    float* posout = (float*)(ws + 2 * anchorBytes + partBytes);          // 128 KB
    const size_t posBytes = (size_t)BSZ * 4 * sizeof(float);
    double* partial = (double*)(ws + 2 * anchorBytes + partBytes + posBytes); // 512 B

    norm_kernel<<<BSZ / 4, 256, 0, stream>>>(feat, anchor, anchorT);
    simloss_kernel<<<NTRI, 256, 0, stream>>>(anchorT, part);
    posfix_kernel<<<NCLS, 256, 0, stream>>>(anchor, labels, posout);
    reduce_kernel<<<BSZ / 256, 256, 0, stream>>>(part, posout, partial);
    final_kernel<<<1, 64, 0, stream>>>(partial, out);
}